// Round 8
// baseline (276.020 us; speedup 1.0000x reference)
//
#include <hip/hip_runtime.h>
#include <stdint.h>

// Problem constants (fixed by reference)
#define B_  8
#define C_  384
#define N_  1600
#define R_  4
#define S_  160
#define HW_ 40

typedef float  f32x4  __attribute__((ext_vector_type(4)));
typedef __bf16 bf16x8 __attribute__((ext_vector_type(8)));
typedef long long i64t;

__device__ __forceinline__ unsigned short f2bf(float x){
  __bf16 h = (__bf16)x;                         // RNE
  return __builtin_bit_cast(unsigned short, h);
}
__device__ __forceinline__ float bf2f(unsigned short u){
  return __builtin_bit_cast(float, (uint32_t)u << 16);
}
// pack 4 floats -> 4 OCP e4m3 bytes (v_cvt_pk_fp8_f32 on gfx950 emits OCP)
__device__ __forceinline__ uint32_t pk_fp8x4(float a, float b, float c, float d){
  int lo = __builtin_amdgcn_cvt_pk_fp8_f32(a, b, 0, false);
  int hi = __builtin_amdgcn_cvt_pk_fp8_f32(c, d, 0, false);
  return (uint32_t)(lo & 0xffff) | ((uint32_t)hi << 16);
}

// async global->LDS, 16B per lane; LDS dest is wave-uniform base + lane*16
__device__ __forceinline__ void gload_lds16(const void* g, void* l){
  __builtin_amdgcn_global_load_lds(
      (const __attribute__((address_space(1))) uint32_t*)g,
      (__attribute__((address_space(3))) uint32_t*)l, 16, 0, 0);
}

// ---------------------------------------------------------------- norms ----
__global__ void norm_kernel(const float* __restrict__ feats,
                            const float* __restrict__ refs,
                            float* __restrict__ invn){
  int gid = blockIdx.x * 256 + threadIdx.x;      // 16000 total (4 n per thread)
  if (gid >= 16000) return;
  int mat = gid / 400;
  int n4  = (gid - mat * 400) * 4;
  const float* src = (mat < B_) ? (feats + (size_t)mat * C_ * N_)
                                : (refs  + (size_t)(mat - B_) * C_ * N_);
  f32x4 ss = {0.f,0.f,0.f,0.f};
  for (int c = 0; c < C_; ++c){
    f32x4 v = *(const f32x4*)(src + (size_t)c * N_ + n4);
    ss += v * v;
  }
  f32x4 r;
#pragma unroll
  for (int i = 0; i < 4; ++i) r[i] = 1.f / fmaxf(sqrtf(ss[i]), 1e-12f);
  *(f32x4*)(invn + (size_t)mat * N_ + n4) = r;
}

// ----------------------------------------------------- transpose/convert ----
// Qb [b][n][c] fp8 normalized; Kb [rb][n][c] fp8 normalized; Vb [rb][c][n] bf16 raw
__global__ void prep_kernel(const float* __restrict__ feats,
                            const float* __restrict__ refs,
                            const float* __restrict__ invn,
                            unsigned char* __restrict__ Qb,
                            unsigned char* __restrict__ Kb,
                            unsigned short* __restrict__ Vb){
  int nt = blockIdx.x, ct = blockIdx.y, mat = blockIdx.z;
  __shared__ float tile[64][65];
  int t = threadIdx.x;
  bool isref = (mat >= B_);
  const float* src = isref ? refs  + (size_t)(mat - B_) * C_ * N_
                           : feats + (size_t)mat * C_ * N_;
#pragma unroll
  for (int i = 0; i < 4; ++i){
    int chunk = t + 256 * i;                      // 0..1023
    int cr = chunk >> 4, n4 = chunk & 15;
    size_t off = (size_t)(ct * 64 + cr) * N_ + nt * 64 + n4 * 4;
    float4 v = *(const float4*)(src + off);
    tile[cr][n4 * 4 + 0] = v.x;  tile[cr][n4 * 4 + 1] = v.y;
    tile[cr][n4 * 4 + 2] = v.z;  tile[cr][n4 * 4 + 3] = v.w;
    if (isref){
      ushort4 o;
      o.x = f2bf(v.x); o.y = f2bf(v.y); o.z = f2bf(v.z); o.w = f2bf(v.w);
      unsigned short* vdst = Vb + (size_t)(mat - B_) * C_ * N_;
      *(ushort4*)(vdst + off) = o;
    }
  }
  __syncthreads();
  unsigned char* dst = isref ? Kb + (size_t)(mat - B_) * N_ * C_
                             : Qb + (size_t)mat * N_ * C_;
  const float* ivp = invn + (size_t)mat * N_ + nt * 64;
#pragma unroll
  for (int i = 0; i < 4; ++i){
    int chunk = t + 256 * i;
    int nr = chunk >> 4, c4 = chunk & 15;
    float iv = ivp[nr];
    uint32_t pk = pk_fp8x4(tile[c4*4+0][nr] * iv, tile[c4*4+1][nr] * iv,
                           tile[c4*4+2][nr] * iv, tile[c4*4+3][nr] * iv);
    *(uint32_t*)(dst + (size_t)(nt*64+nr) * C_ + ct*64 + c4*4) = pk;
  }
}

// ------------------------------------------------------------------ mask ----
__global__ void mask_kernel(const float* __restrict__ sopm,
                            float* __restrict__ maskp){
  int gid = blockIdx.x * 256 + threadIdx.x;       // 12800
  int b = gid / N_, n = gid - b * N_;
  int oy = n / HW_, ox = n - oy * HW_;
  const float* sp = sopm + (size_t)b * S_ * S_;
  float cy = oy * 4 + 1.5f, cx = ox * 4 + 1.5f;
  int y0 = 4*oy - 2; if (y0 < 0) y0 = 0;
  int y1 = 4*oy + 5; if (y1 > S_-1) y1 = S_-1;
  int x0 = 4*ox - 2; if (x0 < 0) x0 = 0;
  int x1 = 4*ox + 5; if (x1 > S_-1) x1 = S_-1;
  float wsy = 0.f, wsx = 0.f;
  for (int j = y0; j <= y1; ++j) wsy += 1.f - fabsf(j - cy) * 0.25f;
  for (int j = x0; j <= x1; ++j) wsx += 1.f - fabsf(j - cx) * 0.25f;
  float acc = 0.f;
  for (int jy = y0; jy <= y1; ++jy){
    float wy = 1.f - fabsf(jy - cy) * 0.25f;
    float rs = 0.f;
    for (int jx = x0; jx <= x1; ++jx)
      rs += (1.f - fabsf(jx - cx) * 0.25f) * sp[jy * S_ + jx];
    acc += wy * rs;
  }
  float val = acc / (wsy * wsx);
  maskp[gid] = (val > 0.3f) ? 1.f : 0.f;
}

// ------------------------------------------------------------- attention ----
// grid 800 = (r*B+b)*25 + qtile (XCD-swizzled). Block: 4 waves.
// QK 2x2 wave-split: wave (mw=w>>1, qw=w&1) computes sim[mw*16..+16][qw*32..+32]
//   (Q fp8 frags for 32 q in regs; each K row read by 2 waves, not 4).
// V NEVER in LDS: PV B-frag = V[m=lg*8..+8][c] is a contiguous 16B global load
//   per lane ([c][m] layout) — issued at iter top, L2-resident per rb.
// P block-shared [64q][32m] bf16 (swizzled). PV c-split: wave w owns c=w*96..+96.
// 3 barriers/iter: QK | bar1 | stageK(t+1), softmax, P-write, lgkm0 | bar2 |
//   pa-read, PV | vmcnt0 | bar3.
// LDS 16 KB (K 12K + P 4K). launch_bounds(256,2): ~222 live regs needs the
// 256 cap (the (256,3)/170 cap spilled the O accumulator twice: R2, R6).
#define P_OFF  12288
#define LDS_SZ 16384

__global__ __launch_bounds__(256, 2) void attn_kernel(
    const unsigned char* __restrict__ Qb,
    const unsigned char* __restrict__ Kb,
    const unsigned short* __restrict__ Vb,
    const float* __restrict__ log_tau,
    unsigned short* __restrict__ Or)
{
  __shared__ __align__(16) char lds[LDS_SZ];
  int wg   = blockIdx.x;
  int orig = (wg & 7) * 100 + (wg >> 3);   // XCD-contiguous chunks (800 = 8*100)
  int qt   = orig % 25;
  int rb   = orig / 25;                    // r*B + b
  int b    = rb & 7;
  int tid  = threadIdx.x;
  int lane = tid & 63;
  int w    = tid >> 6;
  int mw   = w >> 1;                       // m-half for QK
  int qw   = w & 1;                        // q-half for QK
  int l15  = lane & 15;
  int lg   = lane >> 4;

  float tau = expf(log_tau[0]);
  tau = fminf(fmaxf(tau, 0.005f), 0.1f);
  float sc = 1.4426950408889634f / tau;    // log2(e)/tau

  // Q fp8 fragments: 32 q rows (2 q-tiles) in regs (48 VGPR)
  i64t qreg[2][12];
#pragma unroll
  for (int qt2 = 0; qt2 < 2; ++qt2){
    const unsigned char* qp = Qb +
        ((size_t)b * N_ + qt * 64 + qw * 32 + qt2 * 16 + l15) * C_ + lg * 8;
#pragma unroll
    for (int ks = 0; ks < 12; ++ks)
      qreg[qt2][ks] = *(const i64t*)(qp + ks * 32);
  }

  // O accumulator: [qf2 0..3][cf 0..5] -> O[qf2*16 + lg*4 + rg][w*96 + cf*16 + l15]
  f32x4 o[4][6];
#pragma unroll
  for (int i = 0; i < 4; ++i)
#pragma unroll
    for (int j = 0; j < 6; ++j) o[i][j] = (f32x4){0.f,0.f,0.f,0.f};
  float lsum0 = 0.f, lsum1 = 0.f;          // l for q = qw*32 + {l15, 16+l15}

  const unsigned char*  kmat = Kb + (size_t)rb * N_ * C_;
  const unsigned short* vmat = Vb + (size_t)rb * C_ * N_;
  char* Pb = lds + P_OFF;                  // block-shared P [64q][64B row]

  // per-lane global byte offsets for the 3 K gload_lds per wave
  int koffB[3];
#pragma unroll
  for (int i = 0; i < 3; ++i){
    int L = (w * 3 + i) * 64 + lane;              // granule 0..767
    int m   = L / 24;
    int pos = L - m * 24;
    int cc  = (pos >> 3) * 8 + ((pos & 7) ^ (m & 7));
    koffB[i] = m * C_ + cc * 16;
  }
  char* kdst = lds + (size_t)(w * 3) * 1024;       // wave-uniform LDS bases

  // per-lane V global row pointers (c = w*96 + cf*16 + l15, m-offset lg*8)
  const unsigned short* vptr[6];
#pragma unroll
  for (int cf = 0; cf < 6; ++cf)
    vptr[cf] = vmat + (size_t)(w * 96 + cf * 16 + l15) * N_ + lg * 8;

  // P offsets: row q (64B), phys granule = logical ^ s(q), s(q) = (l15>>1)&3
  const int s_l  = (l15 >> 1) & 3;
  const int p_w0 = (qw*32      + l15) * 64 + (((2*mw + (lg >> 1)) ^ s_l) << 4) + (lg & 1) * 8;
  const int p_w1 = (qw*32 + 16 + l15) * 64 + (((2*mw + (lg >> 1)) ^ s_l) << 4) + (lg & 1) * 8;
  const int p_rc = ((lg ^ s_l) << 4) + l15 * 64;   // + qf2*1024

  auto stageK = [&](int t){
    const unsigned char* kb = kmat + (size_t)t * 32 * C_;
#pragma unroll
    for (int i = 0; i < 3; ++i) gload_lds16(kb + koffB[i], kdst + i * 1024);
  };

  // prologue: K(0) staged
  stageK(0);
  asm volatile("s_waitcnt vmcnt(0)" ::: "memory");
  __builtin_amdgcn_sched_barrier(0);
  __builtin_amdgcn_s_barrier();
  __builtin_amdgcn_sched_barrier(0);

  const int krow = (mw * 16 + l15);        // K LDS row this lane reads
  for (int mt = 0; mt < 50; ++mt){
    // ---- issue V B-frags for this tile (global, L2-resident; used in PV)
    bf16x8 vf[6];
#pragma unroll
    for (int cf = 0; cf < 6; ++cf){
      vf[cf] = *(const bf16x8*)(vptr[cf]);
      vptr[cf] += 32;
    }
    __builtin_amdgcn_sched_barrier(0);     // keep V issue ahead of QK

    // ---- QK^T fp8 (swapped): sim[mw-tile][qw 32q], 12 a-loads, 24 MFMAs
    f32x4 s0 = {0.f,0.f,0.f,0.f}, s1 = {0.f,0.f,0.f,0.f};
    __builtin_amdgcn_s_setprio(1);
#pragma unroll
    for (int ks = 0; ks < 12; ++ks){
      int lc  = 2 * ks + (lg >> 1);
      int off = ((lc >> 3) * 8 + ((lc & 7) ^ (krow & 7))) * 16 + (lg & 1) * 8;
      i64t a = *(const i64t*)(lds + krow * 384 + off);
      s0 = __builtin_amdgcn_mfma_f32_16x16x32_fp8_fp8(a, qreg[0][ks], s0, 0, 0, 0);
      s1 = __builtin_amdgcn_mfma_f32_16x16x32_fp8_fp8(a, qreg[1][ks], s1, 0, 0, 0);
    }
    __builtin_amdgcn_s_setprio(0);

    __builtin_amdgcn_sched_barrier(0);
    __builtin_amdgcn_s_barrier();          // all waves done reading K(mt)
    __builtin_amdgcn_sched_barrier(0);
    if (mt < 49) stageK(mt + 1);           // overlaps softmax + PV below

    // ---- P = exp2((sim-1)*log2e/tau), quantize bf16, accumulate l per q
    ushort4 pw0, pw1;
    {
      __bf16 h;
      float l0 = 0.f, l1 = 0.f;
      h = (__bf16)exp2f((s0[0]-1.f)*sc); l0 += (float)h; pw0.x = __builtin_bit_cast(unsigned short, h);
      h = (__bf16)exp2f((s0[1]-1.f)*sc); l0 += (float)h; pw0.y = __builtin_bit_cast(unsigned short, h);
      h = (__bf16)exp2f((s0[2]-1.f)*sc); l0 += (float)h; pw0.z = __builtin_bit_cast(unsigned short, h);
      h = (__bf16)exp2f((s0[3]-1.f)*sc); l0 += (float)h; pw0.w = __builtin_bit_cast(unsigned short, h);
      h = (__bf16)exp2f((s1[0]-1.f)*sc); l1 += (float)h; pw1.x = __builtin_bit_cast(unsigned short, h);
      h = (__bf16)exp2f((s1[1]-1.f)*sc); l1 += (float)h; pw1.y = __builtin_bit_cast(unsigned short, h);
      h = (__bf16)exp2f((s1[2]-1.f)*sc); l1 += (float)h; pw1.z = __builtin_bit_cast(unsigned short, h);
      h = (__bf16)exp2f((s1[3]-1.f)*sc); l1 += (float)h; pw1.w = __builtin_bit_cast(unsigned short, h);
      lsum0 += l0; lsum1 += l1;
    }
    *(ushort4*)(Pb + p_w0) = pw0;   // q = qw*32+l15,    m = mw*16+lg*4..+3
    *(ushort4*)(Pb + p_w1) = pw1;   // q = qw*32+16+l15, m = mw*16+lg*4..+3
    asm volatile("s_waitcnt lgkmcnt(0)" ::: "memory");
    __builtin_amdgcn_sched_barrier(0);
    __builtin_amdgcn_s_barrier();          // P visible to all waves
    __builtin_amdgcn_sched_barrier(0);

    // ---- PV c-split: O[64q][w*96..+96] += P * V (V from regs; P from LDS)
    bf16x8 pa[4];
#pragma unroll
    for (int qf2 = 0; qf2 < 4; ++qf2)
      pa[qf2] = *(const bf16x8*)(Pb + qf2 * 1024 + p_rc);  // P[qf2*16+l15][lg*8..+7]
    __builtin_amdgcn_s_setprio(1);
#pragma unroll
    for (int cf = 0; cf < 6; ++cf){
#pragma unroll
      for (int qf2 = 0; qf2 < 4; ++qf2)
        o[qf2][cf] = __builtin_amdgcn_mfma_f32_16x16x32_bf16(pa[qf2], vf[cf], o[qf2][cf], 0, 0, 0);
    }
    __builtin_amdgcn_s_setprio(0);

    // drain stageK(t+1) (V regs already consumed), then release iteration
    asm volatile("s_waitcnt vmcnt(0)" ::: "memory");
    __builtin_amdgcn_sched_barrier(0);
    __builtin_amdgcn_s_barrier();          // K(mt+1) ready; P(mt) fully read
    __builtin_amdgcn_sched_barrier(0);
  }

  // ---- finalize: l per q = sum over both m-half waves
  lsum0 += __shfl_xor(lsum0, 16, 64);
  lsum0 += __shfl_xor(lsum0, 32, 64);
  lsum1 += __shfl_xor(lsum1, 16, 64);
  lsum1 += __shfl_xor(lsum1, 32, 64);
  __syncthreads();                         // loop done; K region reusable
  float* lsh = (float*)lds;                // [2 mw][64 q]
  if (lg == 0){
    lsh[mw * 64 + qw * 32 + l15]      = lsum0;
    lsh[mw * 64 + qw * 32 + 16 + l15] = lsum1;
  }
  __syncthreads();
  float invl[4][4];
#pragma unroll
  for (int qf2 = 0; qf2 < 4; ++qf2)
#pragma unroll
    for (int rg = 0; rg < 4; ++rg){
      int q = qf2 * 16 + lg * 4 + rg;
      invl[qf2][rg] = 1.f / (lsh[q] + lsh[64 + q]);
    }

  int qbase = qt * 64;
  unsigned short* op = Or + ((size_t)rb * N_ + qbase) * C_ + w * 96 + l15;
#pragma unroll
  for (int qf2 = 0; qf2 < 4; ++qf2){
#pragma unroll
    for (int cf = 0; cf < 6; ++cf){
#pragma unroll
      for (int rg = 0; rg < 4; ++rg){
        int q = qf2 * 16 + lg * 4 + rg;
        op[(size_t)q * C_ + cf * 16] = f2bf(o[qf2][cf][rg] * invl[qf2][rg]);
      }
    }
  }
}

// --------------------------------------------------------------- combine ----
// out[b][c][n] = feats + mask*alpha*(sum_r Or/4 - feats); transpose [n][c]->[c][n]
__global__ void combine_kernel(const unsigned short* __restrict__ Or,
                               const float* __restrict__ feats,
                               const float* __restrict__ maskp,
                               const float* __restrict__ alpha_raw,
                               float* __restrict__ out){
  int nt = blockIdx.x, ct = blockIdx.y, b = blockIdx.z;
  __shared__ float tile[64][65];
  float alpha = 1.f / (1.f + expf(-alpha_raw[0]));
  int t = threadIdx.x;
#pragma unroll
  for (int i = 0; i < 4; ++i){
    int chunk = t + 256 * i;
    int nr = chunk >> 4, c4 = chunk & 15;
    size_t base = ((size_t)b * N_ + nt * 64 + nr) * C_ + ct * 64 + c4 * 4;
    float4 s = {0.f,0.f,0.f,0.f};
#pragma unroll
    for (int r = 0; r < 4; ++r){
      ushort4 v = *(const ushort4*)(Or + (size_t)r * B_ * N_ * C_ + base);
      s.x += bf2f(v.x); s.y += bf2f(v.y); s.z += bf2f(v.z); s.w += bf2f(v.w);
    }
    tile[nr][c4*4+0] = s.x; tile[nr][c4*4+1] = s.y;
    tile[nr][c4*4+2] = s.z; tile[nr][c4*4+3] = s.w;
  }
  __syncthreads();
#pragma unroll
  for (int i = 0; i < 4; ++i){
    int chunk = t + 256 * i;
    int cr = chunk >> 4, n4 = chunk & 15;
    size_t fb = ((size_t)b * C_ + ct * 64 + cr) * N_ + nt * 64 + n4 * 4;
    float4 f  = *(const float4*)(feats + fb);
    float4 mk = *(const float4*)(maskp + (size_t)b * N_ + nt * 64 + n4 * 4);
    float4 ov;
    ov.x = f.x + mk.x * alpha * (tile[n4*4+0][cr] * 0.25f - f.x);
    ov.y = f.y + mk.y * alpha * (tile[n4*4+1][cr] * 0.25f - f.y);
    ov.z = f.z + mk.z * alpha * (tile[n4*4+2][cr] * 0.25f - f.z);
    ov.w = f.w + mk.w * alpha * (tile[n4*4+3][cr] * 0.25f - f.w);
    *(float4*)(out + fb) = ov;
  }
}

// ws-too-small sentinel: recognizable absmax ~1e6
__global__ void poison_kernel(float* out, int n){
  int i = blockIdx.x * 256 + threadIdx.x;
  if (i < n) out[i] = 1.0e6f;
}

extern "C" void kernel_launch(void* const* d_in, const int* in_sizes, int n_in,
                              void* d_out, int out_size, void* d_ws, size_t ws_size,
                              hipStream_t stream){
  const float* feats     = (const float*)d_in[0];
  const float* refs      = (const float*)d_in[1];
  const float* sopm      = (const float*)d_in[2];
  const float* log_tau   = (const float*)d_in[3];
  const float* alpha_raw = (const float*)d_in[4];
  float* out = (float*)d_out;

  const size_t SZ_INVN = (size_t)(1 + R_) * B_ * N_ * 4;   //   256,000
  const size_t SZ_MASK = (size_t)B_ * N_ * 4;              //    51,200
  const size_t SZ_QB   = (size_t)B_ * N_ * C_;             // 4,915,200 (fp8)
  const size_t SZ_KB   = (size_t)R_ * B_ * N_ * C_;        // 19,660,800 (fp8)
  const size_t SZ_VB   = (size_t)R_ * B_ * N_ * C_ * 2;    // 39,321,600 (bf16)
  const size_t SZ_OR   = (size_t)R_ * B_ * N_ * C_ * 2;    // 39,321,600 (bf16)
  const size_t need = SZ_INVN + SZ_MASK + SZ_QB + SZ_KB + SZ_VB + SZ_OR;

  if (ws_size < need){
    poison_kernel<<<(out_size + 255) / 256, 256, 0, stream>>>(out, out_size);
    return;
  }
  char* ws = (char*)d_ws;
  float*          invn  = (float*)ws;
  float*          maskp = (float*)(ws + SZ_INVN);
  unsigned char*  Qb    = (unsigned char*)(ws + SZ_INVN + SZ_MASK);
  unsigned char*  Kb    = (unsigned char*)(ws + SZ_INVN + SZ_MASK + SZ_QB);
  unsigned short* Vb    = (unsigned short*)(ws + SZ_INVN + SZ_MASK + SZ_QB + SZ_KB);
  unsigned short* Or    = (unsigned short*)(ws + SZ_INVN + SZ_MASK + SZ_QB + SZ_KB + SZ_VB);

  norm_kernel   <<<63, 256, 0, stream>>>(feats, refs, invn);
  mask_kernel   <<<50, 256, 0, stream>>>(sopm, maskp);
  prep_kernel   <<<dim3(25, 6, 40), 256, 0, stream>>>(feats, refs, invn, Qb, Kb, Vb);
  attn_kernel   <<<800, 256, 0, stream>>>(Qb, Kb, Vb, log_tau, Or);
  combine_kernel<<<dim3(25, 6, 8), 256, 0, stream>>>(Or, feats, maskp, alpha_raw, out);
}

// Round 9
// 222.312 us; speedup vs baseline: 1.2416x; 1.2416x over previous
//
#include <hip/hip_runtime.h>
#include <stdint.h>

// Problem constants (fixed by reference)
#define B_  8
#define C_  384
#define N_  1600
#define R_  4
#define S_  160
#define HW_ 40

typedef float  f32x4  __attribute__((ext_vector_type(4)));
typedef __bf16 bf16x8 __attribute__((ext_vector_type(8)));
typedef long long i64t;

__device__ __forceinline__ unsigned short f2bf(float x){
  __bf16 h = (__bf16)x;                         // RNE
  return __builtin_bit_cast(unsigned short, h);
}
__device__ __forceinline__ float bf2f(unsigned short u){
  return __builtin_bit_cast(float, (uint32_t)u << 16);
}
// pack 4 floats -> 4 OCP e4m3 bytes (v_cvt_pk_fp8_f32 on gfx950 emits OCP)
__device__ __forceinline__ uint32_t pk_fp8x4(float a, float b, float c, float d){
  int lo = __builtin_amdgcn_cvt_pk_fp8_f32(a, b, 0, false);
  int hi = __builtin_amdgcn_cvt_pk_fp8_f32(c, d, 0, false);
  return (uint32_t)(lo & 0xffff) | ((uint32_t)hi << 16);
}

// async global->LDS, 16B per lane; LDS dest is wave-uniform base + lane*16
__device__ __forceinline__ void gload_lds16(const void* g, void* l){
  __builtin_amdgcn_global_load_lds(
      (const __attribute__((address_space(1))) uint32_t*)g,
      (__attribute__((address_space(3))) uint32_t*)l, 16, 0, 0);
}

// ---------------------------------------------------------------- norms ----
__global__ void norm_kernel(const float* __restrict__ feats,
                            const float* __restrict__ refs,
                            float* __restrict__ invn){
  int gid = blockIdx.x * 256 + threadIdx.x;      // 16000 total (4 n per thread)
  if (gid >= 16000) return;
  int mat = gid / 400;
  int n4  = (gid - mat * 400) * 4;
  const float* src = (mat < B_) ? (feats + (size_t)mat * C_ * N_)
                                : (refs  + (size_t)(mat - B_) * C_ * N_);
  f32x4 ss = {0.f,0.f,0.f,0.f};
  for (int c = 0; c < C_; ++c){
    f32x4 v = *(const f32x4*)(src + (size_t)c * N_ + n4);
    ss += v * v;
  }
  f32x4 r;
#pragma unroll
  for (int i = 0; i < 4; ++i) r[i] = 1.f / fmaxf(sqrtf(ss[i]), 1e-12f);
  *(f32x4*)(invn + (size_t)mat * N_ + n4) = r;
}

// ----------------------------------------------------- transpose/convert ----
// Qb [b][n][c] fp8 normalized; Kb [rb][n][c] fp8 normalized; Vb [rb][c][n] bf16 raw
__global__ void prep_kernel(const float* __restrict__ feats,
                            const float* __restrict__ refs,
                            const float* __restrict__ invn,
                            unsigned char* __restrict__ Qb,
                            unsigned char* __restrict__ Kb,
                            unsigned short* __restrict__ Vb){
  int nt = blockIdx.x, ct = blockIdx.y, mat = blockIdx.z;
  __shared__ float tile[64][65];
  int t = threadIdx.x;
  bool isref = (mat >= B_);
  const float* src = isref ? refs  + (size_t)(mat - B_) * C_ * N_
                           : feats + (size_t)mat * C_ * N_;
#pragma unroll
  for (int i = 0; i < 4; ++i){
    int chunk = t + 256 * i;                      // 0..1023
    int cr = chunk >> 4, n4 = chunk & 15;
    size_t off = (size_t)(ct * 64 + cr) * N_ + nt * 64 + n4 * 4;
    float4 v = *(const float4*)(src + off);
    tile[cr][n4 * 4 + 0] = v.x;  tile[cr][n4 * 4 + 1] = v.y;
    tile[cr][n4 * 4 + 2] = v.z;  tile[cr][n4 * 4 + 3] = v.w;
    if (isref){
      ushort4 o;
      o.x = f2bf(v.x); o.y = f2bf(v.y); o.z = f2bf(v.z); o.w = f2bf(v.w);
      unsigned short* vdst = Vb + (size_t)(mat - B_) * C_ * N_;
      *(ushort4*)(vdst + off) = o;
    }
  }
  __syncthreads();
  unsigned char* dst = isref ? Kb + (size_t)(mat - B_) * N_ * C_
                             : Qb + (size_t)mat * N_ * C_;
  const float* ivp = invn + (size_t)mat * N_ + nt * 64;
#pragma unroll
  for (int i = 0; i < 4; ++i){
    int chunk = t + 256 * i;
    int nr = chunk >> 4, c4 = chunk & 15;
    float iv = ivp[nr];
    uint32_t pk = pk_fp8x4(tile[c4*4+0][nr] * iv, tile[c4*4+1][nr] * iv,
                           tile[c4*4+2][nr] * iv, tile[c4*4+3][nr] * iv);
    *(uint32_t*)(dst + (size_t)(nt*64+nr) * C_ + ct*64 + c4*4) = pk;
  }
}

// ------------------------------------------------------------------ mask ----
__global__ void mask_kernel(const float* __restrict__ sopm,
                            float* __restrict__ maskp){
  int gid = blockIdx.x * 256 + threadIdx.x;       // 12800
  int b = gid / N_, n = gid - b * N_;
  int oy = n / HW_, ox = n - oy * HW_;
  const float* sp = sopm + (size_t)b * S_ * S_;
  float cy = oy * 4 + 1.5f, cx = ox * 4 + 1.5f;
  int y0 = 4*oy - 2; if (y0 < 0) y0 = 0;
  int y1 = 4*oy + 5; if (y1 > S_-1) y1 = S_-1;
  int x0 = 4*ox - 2; if (x0 < 0) x0 = 0;
  int x1 = 4*ox + 5; if (x1 > S_-1) x1 = S_-1;
  float wsy = 0.f, wsx = 0.f;
  for (int j = y0; j <= y1; ++j) wsy += 1.f - fabsf(j - cy) * 0.25f;
  for (int j = x0; j <= x1; ++j) wsx += 1.f - fabsf(j - cx) * 0.25f;
  float acc = 0.f;
  for (int jy = y0; jy <= y1; ++jy){
    float wy = 1.f - fabsf(jy - cy) * 0.25f;
    float rs = 0.f;
    for (int jx = x0; jx <= x1; ++jx)
      rs += (1.f - fabsf(jx - cx) * 0.25f) * sp[jy * S_ + jx];
    acc += wy * rs;
  }
  float val = acc / (wsy * wsx);
  maskp[gid] = (val > 0.3f) ? 1.f : 0.f;
}

// ------------------------------------------------------------- attention ----
// grid 800 = (r*B+b)*25 + qtile (XCD-swizzled). Block: 4 waves.
// QK 2x2 wave-split: wave (mw=w>>1, qw=w&1) computes sim[mw*16..+16][qw*32..+32].
// P block-shared [64q][32m] bf16 (swizzled). PV c-split: wave w owns c=w*96..+96;
// V in LDS (each byte read once). K and V DOUBLE-BUFFERED -> 2 barriers/iter,
// steady-state counted vmcnt(3) (K(t+2) stays in flight; never drained):
//  phase A: stageV(t+1)->vb[cur^1]; QK(kb[cur]); softmax; P-write; lgkm0 | bar1
//  phase B: stageK(t+2)->kb[cur]; pa-read; PV(vb[cur]); vmcnt(3) | bar2
// Clamped restaging in last iters keeps outstanding-op counts uniform.
// LDS: K 2x12K + V 2x24K + P 4K = 76 KB -> 2 blocks/CU. launch_bounds(256,2):
// ~190 live regs needs the 256 cap ((256,3)/170 spilled the acc: R2, R6).
#define KB0_   0
#define KB1_   12288
#define VB0_   24576
#define VB1_   49152
#define P_OFF  73728
#define LDS_SZ 77824

__global__ __launch_bounds__(256, 2) void attn_kernel(
    const unsigned char* __restrict__ Qb,
    const unsigned char* __restrict__ Kb,
    const unsigned short* __restrict__ Vb,
    const float* __restrict__ log_tau,
    unsigned short* __restrict__ Or)
{
  __shared__ __align__(16) char lds[LDS_SZ];
  int wg   = blockIdx.x;
  int orig = (wg & 7) * 100 + (wg >> 3);   // XCD-contiguous chunks (800 = 8*100)
  int qt   = orig % 25;
  int rb   = orig / 25;                    // r*B + b
  int b    = rb & 7;
  int tid  = threadIdx.x;
  int lane = tid & 63;
  int w    = tid >> 6;
  int mw   = w >> 1;                       // m-half for QK
  int qw   = w & 1;                        // q-half for QK
  int l15  = lane & 15;
  int lg   = lane >> 4;

  float tau = expf(log_tau[0]);
  tau = fminf(fmaxf(tau, 0.005f), 0.1f);
  float sc = 1.4426950408889634f / tau;    // log2(e)/tau

  // Q fp8 fragments: 32 q rows (2 q-tiles) in regs (48 VGPR)
  i64t qreg[2][12];
#pragma unroll
  for (int qt2 = 0; qt2 < 2; ++qt2){
    const unsigned char* qp = Qb +
        ((size_t)b * N_ + qt * 64 + qw * 32 + qt2 * 16 + l15) * C_ + lg * 8;
#pragma unroll
    for (int ks = 0; ks < 12; ++ks)
      qreg[qt2][ks] = *(const i64t*)(qp + ks * 32);
  }

  // O accumulator: [qf2 0..3][cf 0..5] -> O[qf2*16 + lg*4 + rg][w*96 + cf*16 + l15]
  f32x4 o[4][6];
#pragma unroll
  for (int i = 0; i < 4; ++i)
#pragma unroll
    for (int j = 0; j < 6; ++j) o[i][j] = (f32x4){0.f,0.f,0.f,0.f};
  float lsum0 = 0.f, lsum1 = 0.f;          // l for q = qw*32 + {l15, 16+l15}

  const unsigned char*  kmat = Kb + (size_t)rb * N_ * C_;
  const unsigned short* vmat = Vb + (size_t)rb * C_ * N_;
  char* Pb = lds + P_OFF;                  // block-shared P [64q][64B row]

  // per-lane global byte offsets for the 3 K gload_lds per wave
  int koffB[3];
#pragma unroll
  for (int i = 0; i < 3; ++i){
    int L = (w * 3 + i) * 64 + lane;              // granule 0..767
    int m   = L / 24;
    int pos = L - m * 24;
    int cc  = (pos >> 3) * 8 + ((pos & 7) ^ (m & 7));
    koffB[i] = m * C_ + cc * 16;
  }
  // per-lane global element offsets for the 6 V gload_lds per wave
  int voff[6];
#pragma unroll
  for (int i = 0; i < 6; ++i){
    int chunk = (w * 6 + i) * 64 + lane;          // 0..1535
    int line = chunk >> 3;
    int u    = (chunk & 7) ^ (line & 7);
    voff[i]  = (line * 2 + (u >> 2)) * N_ + (u & 3) * 8;
  }

  // P offsets: row q (64B), phys granule = logical ^ s(q), s(q) = (l15>>1)&3
  const int s_l  = (l15 >> 1) & 3;
  const int p_w0 = (qw*32      + l15) * 64 + (((2*mw + (lg >> 1)) ^ s_l) << 4) + (lg & 1) * 8;
  const int p_w1 = (qw*32 + 16 + l15) * 64 + (((2*mw + (lg >> 1)) ^ s_l) << 4) + (lg & 1) * 8;
  const int p_rc = ((lg ^ s_l) << 4) + l15 * 64;   // + qf2*1024

  auto stageK = [&](int t, int buf){
    const unsigned char* kb = kmat + (size_t)t * 32 * C_;
    char* kdst = lds + (buf ? KB1_ : KB0_) + w * 3072;
#pragma unroll
    for (int i = 0; i < 3; ++i) gload_lds16(kb + koffB[i], kdst + i * 1024);
  };
  auto stageV = [&](int t, int buf){
    const unsigned short* vb = vmat + t * 32;
    char* vdst = lds + (buf ? VB1_ : VB0_) + w * 6144;
#pragma unroll
    for (int i = 0; i < 6; ++i) gload_lds16(vb + voff[i], vdst + i * 1024);
  };

  // prologue: K0->kb0, V0->vb0, K1->kb1; wait K0+V0 (K1 stays in flight)
  stageK(0, 0);
  stageV(0, 0);
  stageK(1, 1);
  asm volatile("s_waitcnt vmcnt(3)" ::: "memory");
  __builtin_amdgcn_sched_barrier(0);
  __builtin_amdgcn_s_barrier();
  __builtin_amdgcn_sched_barrier(0);

  const int krow = (mw * 16 + l15);        // K LDS row this lane reads
  for (int mt = 0; mt < 50; ++mt){
    int cur = mt & 1;
    const char* kbR = lds + (cur ? KB1_ : KB0_);
    const char* vbR = lds + (cur ? VB1_ : VB0_);

    // ---- phase A: issue V(t+1) into the other V buffer (clamped restage
    //      keeps vmcnt counts uniform; dead writes land in a consumed buffer)
    int tv = (mt + 1 < 50) ? mt + 1 : 49;
    stageV(tv, cur ^ 1);
    __builtin_amdgcn_sched_barrier(0);

    // ---- QK^T fp8 (swapped): sim[mw-tile][qw 32q], 12 a-loads, 24 MFMAs
    f32x4 s0 = {0.f,0.f,0.f,0.f}, s1 = {0.f,0.f,0.f,0.f};
    __builtin_amdgcn_s_setprio(1);
#pragma unroll
    for (int ks = 0; ks < 12; ++ks){
      int lc  = 2 * ks + (lg >> 1);
      int off = ((lc >> 3) * 8 + ((lc & 7) ^ (krow & 7))) * 16 + (lg & 1) * 8;
      i64t a = *(const i64t*)(kbR + krow * 384 + off);
      s0 = __builtin_amdgcn_mfma_f32_16x16x32_fp8_fp8(a, qreg[0][ks], s0, 0, 0, 0);
      s1 = __builtin_amdgcn_mfma_f32_16x16x32_fp8_fp8(a, qreg[1][ks], s1, 0, 0, 0);
    }
    __builtin_amdgcn_s_setprio(0);

    // ---- P = exp2((sim-1)*log2e/tau), quantize bf16, accumulate l per q
    ushort4 pw0, pw1;
    {
      __bf16 h;
      float l0 = 0.f, l1 = 0.f;
      h = (__bf16)exp2f((s0[0]-1.f)*sc); l0 += (float)h; pw0.x = __builtin_bit_cast(unsigned short, h);
      h = (__bf16)exp2f((s0[1]-1.f)*sc); l0 += (float)h; pw0.y = __builtin_bit_cast(unsigned short, h);
      h = (__bf16)exp2f((s0[2]-1.f)*sc); l0 += (float)h; pw0.z = __builtin_bit_cast(unsigned short, h);
      h = (__bf16)exp2f((s0[3]-1.f)*sc); l0 += (float)h; pw0.w = __builtin_bit_cast(unsigned short, h);
      h = (__bf16)exp2f((s1[0]-1.f)*sc); l1 += (float)h; pw1.x = __builtin_bit_cast(unsigned short, h);
      h = (__bf16)exp2f((s1[1]-1.f)*sc); l1 += (float)h; pw1.y = __builtin_bit_cast(unsigned short, h);
      h = (__bf16)exp2f((s1[2]-1.f)*sc); l1 += (float)h; pw1.z = __builtin_bit_cast(unsigned short, h);
      h = (__bf16)exp2f((s1[3]-1.f)*sc); l1 += (float)h; pw1.w = __builtin_bit_cast(unsigned short, h);
      lsum0 += l0; lsum1 += l1;
    }
    *(ushort4*)(Pb + p_w0) = pw0;   // q = qw*32+l15,    m = mw*16+lg*4..+3
    *(ushort4*)(Pb + p_w1) = pw1;   // q = qw*32+16+l15, m = mw*16+lg*4..+3
    asm volatile("s_waitcnt lgkmcnt(0)" ::: "memory");
    __builtin_amdgcn_sched_barrier(0);
    __builtin_amdgcn_s_barrier();          // bar1: P visible; K(t) fully read
    __builtin_amdgcn_sched_barrier(0);

    // ---- phase B: issue K(t+2) into kb[cur] (its readers just finished)
    int tk = (mt + 2 < 50) ? mt + 2 : mt;
    stageK(tk, cur);
    __builtin_amdgcn_sched_barrier(0);

    // ---- PV c-split: O[64q][w*96..+96] += P * V (P + V from LDS)
    bf16x8 pa[4];
#pragma unroll
    for (int qf2 = 0; qf2 < 4; ++qf2)
      pa[qf2] = *(const bf16x8*)(Pb + qf2 * 1024 + p_rc);  // P[qf2*16+l15][lg*8..+7]
    __builtin_amdgcn_s_setprio(1);
#pragma unroll
    for (int cf = 0; cf < 6; ++cf){
      int c  = w * 96 + cf * 16 + l15;
      int vo = (c >> 1) * 128 + (((lg | ((c & 1) << 2)) ^ ((c >> 1) & 7)) << 4);
      bf16x8 vf = *(const bf16x8*)(vbR + vo);
#pragma unroll
      for (int qf2 = 0; qf2 < 4; ++qf2)
        o[qf2][cf] = __builtin_amdgcn_mfma_f32_16x16x32_bf16(pa[qf2], vf, o[qf2][cf], 0, 0, 0);
    }
    __builtin_amdgcn_s_setprio(0);

    // steady state: 12 outstanding {K(t+1):3, V(t+1):6, K(t+2):3};
    // wait the oldest 9 -> K(t+1), V(t+1) landed; K(t+2) stays in flight
    asm volatile("s_waitcnt vmcnt(3)" ::: "memory");
    __builtin_amdgcn_sched_barrier(0);
    __builtin_amdgcn_s_barrier();          // bar2: next tile ready; P/V free
    __builtin_amdgcn_sched_barrier(0);
  }

  // ---- finalize: l per q = sum over both m-half waves
  lsum0 += __shfl_xor(lsum0, 16, 64);
  lsum0 += __shfl_xor(lsum0, 32, 64);
  lsum1 += __shfl_xor(lsum1, 16, 64);
  lsum1 += __shfl_xor(lsum1, 32, 64);
  __syncthreads();                         // loop done; K region reusable
  float* lsh = (float*)lds;                // [2 mw][64 q]
  if (lg == 0){
    lsh[mw * 64 + qw * 32 + l15]      = lsum0;
    lsh[mw * 64 + qw * 32 + 16 + l15] = lsum1;
  }
  __syncthreads();
  float invl[4][4];
#pragma unroll
  for (int qf2 = 0; qf2 < 4; ++qf2)
#pragma unroll
    for (int rg = 0; rg < 4; ++rg){
      int q = qf2 * 16 + lg * 4 + rg;
      invl[qf2][rg] = 1.f / (lsh[q] + lsh[64 + q]);
    }

  int qbase = qt * 64;
  unsigned short* op = Or + ((size_t)rb * N_ + qbase) * C_ + w * 96 + l15;
#pragma unroll
  for (int qf2 = 0; qf2 < 4; ++qf2){
#pragma unroll
    for (int cf = 0; cf < 6; ++cf){
#pragma unroll
      for (int rg = 0; rg < 4; ++rg){
        int q = qf2 * 16 + lg * 4 + rg;
        op[(size_t)q * C_ + cf * 16] = f2bf(o[qf2][cf][rg] * invl[qf2][rg]);
      }
    }
  }
}

// --------------------------------------------------------------- combine ----
// out[b][c][n] = feats + mask*alpha*(sum_r Or/4 - feats); transpose [n][c]->[c][n]
__global__ void combine_kernel(const unsigned short* __restrict__ Or,
                               const float* __restrict__ feats,
                               const float* __restrict__ maskp,
                               const float* __restrict__ alpha_raw,
                               float* __restrict__ out){
  int nt = blockIdx.x, ct = blockIdx.y, b = blockIdx.z;
  __shared__ float tile[64][65];
  float alpha = 1.f / (1.f + expf(-alpha_raw[0]));
  int t = threadIdx.x;
#pragma unroll
  for (int i = 0; i < 4; ++i){
    int chunk = t + 256 * i;
    int nr = chunk >> 4, c4 = chunk & 15;
    size_t base = ((size_t)b * N_ + nt * 64 + nr) * C_ + ct * 64 + c4 * 4;
    float4 s = {0.f,0.f,0.f,0.f};
#pragma unroll
    for (int r = 0; r < 4; ++r){
      ushort4 v = *(const ushort4*)(Or + (size_t)r * B_ * N_ * C_ + base);
      s.x += bf2f(v.x); s.y += bf2f(v.y); s.z += bf2f(v.z); s.w += bf2f(v.w);
    }
    tile[nr][c4*4+0] = s.x; tile[nr][c4*4+1] = s.y;
    tile[nr][c4*4+2] = s.z; tile[nr][c4*4+3] = s.w;
  }
  __syncthreads();
#pragma unroll
  for (int i = 0; i < 4; ++i){
    int chunk = t + 256 * i;
    int cr = chunk >> 4, n4 = chunk & 15;
    size_t fb = ((size_t)b * C_ + ct * 64 + cr) * N_ + nt * 64 + n4 * 4;
    float4 f  = *(const float4*)(feats + fb);
    float4 mk = *(const float4*)(maskp + (size_t)b * N_ + nt * 64 + n4 * 4);
    float4 ov;
    ov.x = f.x + mk.x * alpha * (tile[n4*4+0][cr] * 0.25f - f.x);
    ov.y = f.y + mk.y * alpha * (tile[n4*4+1][cr] * 0.25f - f.y);
    ov.z = f.z + mk.z * alpha * (tile[n4*4+2][cr] * 0.25f - f.z);
    ov.w = f.w + mk.w * alpha * (tile[n4*4+3][cr] * 0.25f - f.w);
    *(float4*)(out + fb) = ov;
  }
}

// ws-too-small sentinel: recognizable absmax ~1e6
__global__ void poison_kernel(float* out, int n){
  int i = blockIdx.x * 256 + threadIdx.x;
  if (i < n) out[i] = 1.0e6f;
}

extern "C" void kernel_launch(void* const* d_in, const int* in_sizes, int n_in,
                              void* d_out, int out_size, void* d_ws, size_t ws_size,
                              hipStream_t stream){
  const float* feats     = (const float*)d_in[0];
  const float* refs      = (const float*)d_in[1];
  const float* sopm      = (const float*)d_in[2];
  const float* log_tau   = (const float*)d_in[3];
  const float* alpha_raw = (const float*)d_in[4];
  float* out = (float*)d_out;

  const size_t SZ_INVN = (size_t)(1 + R_) * B_ * N_ * 4;   //   256,000
  const size_t SZ_MASK = (size_t)B_ * N_ * 4;              //    51,200
  const size_t SZ_QB   = (size_t)B_ * N_ * C_;             // 4,915,200 (fp8)
  const size_t SZ_KB   = (size_t)R_ * B_ * N_ * C_;        // 19,660,800 (fp8)
  const size_t SZ_VB   = (size_t)R_ * B_ * N_ * C_ * 2;    // 39,321,600 (bf16)
  const size_t SZ_OR   = (size_t)R_ * B_ * N_ * C_ * 2;    // 39,321,600 (bf16)
  const size_t need = SZ_INVN + SZ_MASK + SZ_QB + SZ_KB + SZ_VB + SZ_OR;

  if (ws_size < need){
    poison_kernel<<<(out_size + 255) / 256, 256, 0, stream>>>(out, out_size);
    return;
  }
  char* ws = (char*)d_ws;
  float*          invn  = (float*)ws;
  float*          maskp = (float*)(ws + SZ_INVN);
  unsigned char*  Qb    = (unsigned char*)(ws + SZ_INVN + SZ_MASK);
  unsigned char*  Kb    = (unsigned char*)(ws + SZ_INVN + SZ_MASK + SZ_QB);
  unsigned short* Vb    = (unsigned short*)(ws + SZ_INVN + SZ_MASK + SZ_QB + SZ_KB);
  unsigned short* Or    = (unsigned short*)(ws + SZ_INVN + SZ_MASK + SZ_QB + SZ_KB + SZ_VB);

  norm_kernel   <<<63, 256, 0, stream>>>(feats, refs, invn);
  mask_kernel   <<<50, 256, 0, stream>>>(sopm, maskp);
  prep_kernel   <<<dim3(25, 6, 40), 256, 0, stream>>>(feats, refs, invn, Qb, Kb, Vb);
  attn_kernel   <<<800, 256, 0, stream>>>(Qb, Kb, Vb, log_tau, Or);
  combine_kernel<<<dim3(25, 6, 8), 256, 0, stream>>>(Or, feats, maskp, alpha_raw, out);
}